// Round 6
// baseline (2192.254 us; speedup 1.0000x reference)
//
#include <hip/hip_runtime.h>

// Problem constants: B=64, S=512, E=512, H=512, V=32000, T=2, L=1
// Output depends ONLY on batch sample 63 (lstm_out[-1] == last batch element).

typedef float f32x4 __attribute__((ext_vector_type(4)));
typedef unsigned long long u64;

#define NB 64   // persistent blocks for the recurrence

// ---------------------------------------------------------------------------
// Kernel 1: xg[t][g] = sum_e emb[sent[63][t]][e] * W_ih[g][e] + b_ih[g]+b_hh[g]
// M=512 (t), N=2048 (g), K=512. Both operands K-major (NT GEMM). (unchanged)
// ---------------------------------------------------------------------------
__global__ __launch_bounds__(256) void xg_gemm_k(
    const int* __restrict__ sent, const float* __restrict__ emb,
    const float* __restrict__ W_ih, const float* __restrict__ b_ih,
    const float* __restrict__ b_hh, float* __restrict__ xg)
{
    __shared__ float As[16][65];   // [k][m]
    __shared__ float Bs[16][65];   // [k][n]
    __shared__ int aidx[64];
    const int tid = threadIdx.x;
    const int t0 = blockIdx.x * 64;
    const int n0 = blockIdx.y * 64;
    if (tid < 64) aidx[tid] = sent[63 * 512 + t0 + tid];
    __syncthreads();

    const int kk = tid & 15;   // k within tile
    const int mm = tid >> 4;   // 0..15
    const int tx = tid & 15, ty = tid >> 4;
    float acc[4][4] = {};

    for (int kb = 0; kb < 512; kb += 16) {
        #pragma unroll
        for (int j = 0; j < 4; j++) {
            int m = mm + j * 16;
            As[kk][m] = emb[(size_t)aidx[m] * 512 + kb + kk];
            Bs[kk][m] = W_ih[(size_t)(n0 + m) * 512 + kb + kk];
        }
        __syncthreads();
        #pragma unroll
        for (int k = 0; k < 16; k++) {
            float a[4], bv[4];
            #pragma unroll
            for (int i = 0; i < 4; i++) a[i] = As[k][ty * 4 + i];
            #pragma unroll
            for (int j = 0; j < 4; j++) bv[j] = Bs[k][tx * 4 + j];
            #pragma unroll
            for (int i = 0; i < 4; i++)
                #pragma unroll
                for (int j = 0; j < 4; j++)
                    acc[i][j] += a[i] * bv[j];
        }
        __syncthreads();
    }

    #pragma unroll
    for (int i = 0; i < 4; i++) {
        int t = t0 + ty * 4 + i;
        #pragma unroll
        for (int j = 0; j < 4; j++) {
            int col = n0 + tx * 4 + j;
            xg[(size_t)t * 2048 + col] = acc[i][j] + b_ih[col] + b_hh[col];
        }
    }
}

// ---------------------------------------------------------------------------
// Kernel 2: persistent batch-1 LSTM recurrence, 512 steps, 64 blocks x 256.
// Block b owns h-indices [b*8, b*8+8). Wave wv owns j = b*8 + 2*wv + {0,1}
// (8 gate rows: q*512 + j for q=0..3). Lane l owns cols {64k + l, k=0..7}.
//
// Handoff (PROVEN protocol, byte-identical semantics): h values travel as
// tagged 64-bit slots  slot = (u64)(t+1)<<32 | float_bits(h_t), relaxed
// agent-scope 8B atomic stores; readers poll the slots themselves; two slot
// arrays ping-pong by step parity; no fences. Safety at wave granularity:
// a wave publishes tag t+1 only after it has READ every tag-t slot, so no
// producer can overwrite a buffer a lagging reader still needs (same
// induction as the original block-level proof).
//
// Design changes vs 838us baseline (post-mortems r2-r5):
//  * Weights: per-lane PRIVATE LDS strip (68-float padded), staged once at
//    init, re-read every step with ds_read_b128 (~120cy latency). Replaces
//    the measured ~1000cy/step serialized L2/scratch weight stream. The
//    register allocator provably (r0/r2/r4/r5: VGPR 60/88/60/40) refuses to
//    keep weight arrays resident across the poll -- LDS sidesteps it. A
//    "memory" clobber after h-acquisition stops LICM turning the LDS reads
//    back into loop-carried (spilled) registers.
//  * ZERO barriers: every wave polls all 512 slots itself (8 coalesced
//    loads: slot[64k+l], lanes contiguous), h goes straight into registers,
//    full 64-lane butterfly gives every lane all 8 row sums, lanes 0/1 run
//    the gate tails inline and publish. No LDS h, no gacc, no syncthreads,
//    no intra-block straggler coupling.
// ---------------------------------------------------------------------------
__global__ __launch_bounds__(256, 1) void lstm_seq_k(
    const float* __restrict__ h0, const float* __restrict__ c0,
    const float* __restrict__ W_hh, const float* __restrict__ xg,
    float* __restrict__ hs,
    u64* __restrict__ sA, u64* __restrict__ sB)
{
    __shared__ float wlds[256 * 68];   // per-thread 68-float strip (64 + pad)

    const int tid = threadIdx.x;
    const int b   = blockIdx.x;
    const int wv  = tid >> 6;          // wave 0..3
    const int l   = tid & 63;          // lane 0..63
    const int jc  = b * 8 + 2 * wv;    // first h-index of this wave

    // Stage this lane's 64 weights into its private LDS strip.
    // Row r (q=r>>1, jj=r&1): gate row q*512 + jc + jj, cols {64k + l}.
    // Global reads coalesced across lanes for fixed (r,k).
    {
        float* wp = &wlds[tid * 68];
        #pragma unroll
        for (int r = 0; r < 8; ++r) {
            const int grow = (r >> 1) * 512 + jc + (r & 1);
            const float* src = &W_hh[(size_t)grow * 512 + l];
            #pragma unroll
            for (int k = 0; k < 8; ++k)
                wp[r * 8 + k] = src[k * 64];
        }
    }
    // No barrier: each lane reads only its own strip.

    // c state: meaningful in lanes 0,1 of each wave.
    float creg = c0[63 * 512 + jc + (l & 1)];

    const float* wq = &wlds[tid * 68];

    for (int t = 0; t < 512; ++t) {
        // xg prefetch for the two tail lanes (independent of h).
        float xgp0 = 0.f, xgp1 = 0.f, xgp2 = 0.f, xgp3 = 0.f;
        if (l < 2) {
            const float* xr = &xg[(size_t)t * 2048 + jc + l];
            xgp0 = xr[0]; xgp1 = xr[512]; xgp2 = xr[1024]; xgp3 = xr[1536];
        }

        // h acquisition straight into registers (no LDS, no barrier).
        float h[8];
        if (t == 0) {
            #pragma unroll
            for (int k = 0; k < 8; ++k)
                h[k] = h0[63 * 512 + k * 64 + l];
        } else {
            // Poll tagged slots of step t-1 (tag == t) in buffer (t-1)&1.
            // 8 independent coalesced loads per sweep (lanes contiguous).
            u64* srcb = ((t - 1) & 1) ? sB : sA;
            const unsigned expt = (unsigned)t;
            u64 v[8];
            for (;;) {
                #pragma unroll
                for (int k = 0; k < 8; ++k)
                    v[k] = __hip_atomic_load(&srcb[k * 64 + l],
                             __ATOMIC_RELAXED, __HIP_MEMORY_SCOPE_AGENT);
                bool ok = true;
                #pragma unroll
                for (int k = 0; k < 8; ++k)
                    ok &= ((unsigned)(v[k] >> 32) == expt);
                if (ok) break;
            }
            #pragma unroll
            for (int k = 0; k < 8; ++k)
                h[k] = __uint_as_float((unsigned)v[k]);
        }

        // Stop LICM from hoisting the weight LDS reads into loop-carried
        // registers (the allocator would spill them to scratch -- r2/r4/r5).
        asm volatile("" ::: "memory");

        // 8 rows x 8 cols of FMA from the private LDS strip.
        float acc[8];
        #pragma unroll
        for (int r = 0; r < 8; ++r) {
            f32x4 w0 = *(const f32x4*)&wq[r * 8];
            f32x4 w1 = *(const f32x4*)&wq[r * 8 + 4];
            acc[r] = w0.x * h[0] + w0.y * h[1] + w0.z * h[2] + w0.w * h[3]
                   + w1.x * h[4] + w1.y * h[5] + w1.z * h[6] + w1.w * h[7];
        }

        // Full 64-lane butterfly: every lane ends with all 8 row sums.
        #pragma unroll
        for (int r = 0; r < 8; ++r) {
            #pragma unroll
            for (int m = 32; m >= 1; m >>= 1)
                acc[r] += __shfl_xor(acc[r], m, 64);
        }

        // Gate tails inline on lanes 0,1 of each wave (j = jc + l).
        // acc index r = q*2 + jj, lane l == jj. Torch order: i, f, g, o.
        if (l < 2) {
            float gi = acc[0 + l] + xgp0;
            float gf = acc[2 + l] + xgp1;
            float gc = acc[4 + l] + xgp2;
            float go = acc[6 + l] + xgp3;
            float ii = 1.f / (1.f + __expf(-gi));
            float ff = 1.f / (1.f + __expf(-gf));
            float cc = 1.f - 2.f / (__expf(2.f * gc) + 1.f);   // tanh
            float oo = 1.f / (1.f + __expf(-go));
            float cn = ff * creg + ii * cc;
            creg = cn;
            float th = 1.f - 2.f / (__expf(2.f * cn) + 1.f);   // tanh
            float hval = oo * th;

            // Publish FIRST (critical path), history store after.
            u64* dst = (t & 1) ? sB : sA;
            u64 pv = ((u64)(unsigned)(t + 1) << 32) |
                     (u64)__float_as_uint(hval);
            __hip_atomic_store(&dst[jc + l], pv,
                               __ATOMIC_RELAXED, __HIP_MEMORY_SCOPE_AGENT);

            hs[(size_t)t * 512 + jc + l] = hval;
        }
        // NO fence, NO flag store, NO barrier anywhere in the loop.
    }
}

// ---------------------------------------------------------------------------
// Kernel 3: out[s][u] = hs[s] . W_lin[u] + b_lin[u], S=512, T=2. (unchanged)
// ---------------------------------------------------------------------------
__global__ __launch_bounds__(256) void final_linear_k(
    const float* __restrict__ hs, const float* __restrict__ W_lin,
    const float* __restrict__ b_lin, float* __restrict__ out)
{
    const int tid = threadIdx.x;
    const int wave = tid >> 6;
    const int lane = tid & 63;
    const int s = blockIdx.x * 4 + wave;
    const float* h = hs + (size_t)s * 512;
    float a0 = 0.f, a1 = 0.f;
    #pragma unroll
    for (int k0 = 0; k0 < 512; k0 += 64) {
        float hv = h[k0 + lane];
        a0 += hv * W_lin[k0 + lane];
        a1 += hv * W_lin[512 + k0 + lane];
    }
    #pragma unroll
    for (int m = 32; m >= 1; m >>= 1) {
        a0 += __shfl_xor(a0, m, 64);
        a1 += __shfl_xor(a1, m, 64);
    }
    if (lane == 0) {
        out[s * 2]     = a0 + b_lin[0];
        out[s * 2 + 1] = a1 + b_lin[1];
    }
}

// ---------------------------------------------------------------------------
extern "C" void kernel_launch(void* const* d_in, const int* in_sizes, int n_in,
                              void* d_out, int out_size, void* d_ws, size_t ws_size,
                              hipStream_t stream)
{
    const int*   sent  = (const int*)d_in[0];     // [64,512] int32
    const float* h0    = (const float*)d_in[1];   // [1,64,512]
    const float* c0    = (const float*)d_in[2];   // [1,64,512]
    const float* emb   = (const float*)d_in[3];   // [32000,512]
    const float* W_ih  = (const float*)d_in[4];   // [2048,512]
    const float* W_hh  = (const float*)d_in[5];   // [2048,512]
    const float* b_ih  = (const float*)d_in[6];   // [2048]
    const float* b_hh  = (const float*)d_in[7];   // [2048]
    const float* W_lin = (const float*)d_in[8];   // [2,512]
    const float* b_lin = (const float*)d_in[9];   // [2]
    float* out = (float*)d_out;                   // [512,2]

    char* ws = (char*)d_ws;
    float* xg = (float*)ws;                                   // 4 MB: [512,2048]
    float* hs = (float*)(ws + 4 * 1024 * 1024);               // 1 MB: [512,512]
    u64* sA = (u64*)(ws + 5 * 1024 * 1024);                   // 4 KB
    u64* sB = (u64*)(ws + 5 * 1024 * 1024 + 4096);            // 4 KB

    // Clear slot tags (0 != any expected tag 1..512).
    hipMemsetAsync(sA, 0, 2 * 4096, stream);

    dim3 g1(8, 32);
    xg_gemm_k<<<g1, 256, 0, stream>>>(sent, emb, W_ih, b_ih, b_hh, xg);
    lstm_seq_k<<<NB, 256, 0, stream>>>(h0, c0, W_hh, xg, hs, sA, sB);
    final_linear_k<<<128, 256, 0, stream>>>(hs, W_lin, b_lin, out);
}

// Round 7
// 1096.903 us; speedup vs baseline: 1.9986x; 1.9986x over previous
//
#include <hip/hip_runtime.h>

// Problem constants: B=64, S=512, E=512, H=512, V=32000, T=2, L=1
// Output depends ONLY on batch sample 63 (lstm_out[-1] == last batch element).

typedef float f32x4 __attribute__((ext_vector_type(4)));
typedef unsigned long long u64;

#define NB 64   // persistent blocks for the recurrence

// LDS h-buffer swizzle: 32 groups of 16 floats, padded to stride 20 words
// (80 B = 5 banks*16B) -> float4 reads stay 16B-aligned, 16-way conflict -> 4-way.
#define HIDX(e) ((((e) >> 4) * 20) + ((e) & 15))

// ---------------------------------------------------------------------------
// Kernel 1: xg[t][g] = sum_e emb[sent[63][t]][e] * W_ih[g][e] + b_ih[g]+b_hh[g]
// M=512 (t), N=2048 (g), K=512. Both operands K-major (NT GEMM). (unchanged)
// ---------------------------------------------------------------------------
__global__ __launch_bounds__(256) void xg_gemm_k(
    const int* __restrict__ sent, const float* __restrict__ emb,
    const float* __restrict__ W_ih, const float* __restrict__ b_ih,
    const float* __restrict__ b_hh, float* __restrict__ xg)
{
    __shared__ float As[16][65];   // [k][m]
    __shared__ float Bs[16][65];   // [k][n]
    __shared__ int aidx[64];
    const int tid = threadIdx.x;
    const int t0 = blockIdx.x * 64;
    const int n0 = blockIdx.y * 64;
    if (tid < 64) aidx[tid] = sent[63 * 512 + t0 + tid];
    __syncthreads();

    const int kk = tid & 15;   // k within tile
    const int mm = tid >> 4;   // 0..15
    const int tx = tid & 15, ty = tid >> 4;
    float acc[4][4] = {};

    for (int kb = 0; kb < 512; kb += 16) {
        #pragma unroll
        for (int j = 0; j < 4; j++) {
            int m = mm + j * 16;
            As[kk][m] = emb[(size_t)aidx[m] * 512 + kb + kk];
            Bs[kk][m] = W_ih[(size_t)(n0 + m) * 512 + kb + kk];
        }
        __syncthreads();
        #pragma unroll
        for (int k = 0; k < 16; k++) {
            float a[4], bv[4];
            #pragma unroll
            for (int i = 0; i < 4; i++) a[i] = As[k][ty * 4 + i];
            #pragma unroll
            for (int j = 0; j < 4; j++) bv[j] = Bs[k][tx * 4 + j];
            #pragma unroll
            for (int i = 0; i < 4; i++)
                #pragma unroll
                for (int j = 0; j < 4; j++)
                    acc[i][j] += a[i] * bv[j];
        }
        __syncthreads();
    }

    #pragma unroll
    for (int i = 0; i < 4; i++) {
        int t = t0 + ty * 4 + i;
        #pragma unroll
        for (int j = 0; j < 4; j++) {
            int col = n0 + tx * 4 + j;
            xg[(size_t)t * 2048 + col] = acc[i][j] + b_ih[col] + b_hh[col];
        }
    }
}

// ---------------------------------------------------------------------------
// Kernel 2: persistent batch-1 LSTM recurrence, 512 steps, 64 blocks x 256.
// Block b owns h-indices [b*8, b*8+8) -> 32 gate rows {q*512 + b*8 + j}.
//
// EXACT round-0 structure (838us, proven): tagged 64-bit slots
//   slot = (u64)(t+1) << 32 | float_bits(h_t)
// relaxed agent-scope 8B atomic stores, readers poll slot[tid], slot[tid+256],
// two arrays ping-pong by parity, no fences. Two barriers, hbuf broadcast,
// gacc LDS, gate tail on tid<8.
//
// ONE change (r6 evidence: private strips measured 0 bank conflicts; r0-r5
// evidence: allocator refuses register-resident weights at any footprint,
// VGPR 60/88/60/40, every pin attempt spilled to scratch): the per-thread
// 64-float weight slice is staged ONCE into a private 68-float-padded LDS
// strip and re-read each step with ds_read_b128 (~250cy, overlapping FMA)
// instead of the compiler's chunk-serialized ~700-1000cy L2 re-stream in
// the post-barrier critical path. The in-loop __syncthreads() prevents LICM
// from hoisting the ds_reads into (spilled) loop-carried registers.
// ---------------------------------------------------------------------------
__global__ __launch_bounds__(256, 1) void lstm_seq_k(
    const float* __restrict__ h0, const float* __restrict__ c0,
    const float* __restrict__ W_hh, const float* __restrict__ xg,
    float* __restrict__ hs,
    u64* __restrict__ sA, u64* __restrict__ sB)
{
    __shared__ float wlds[256 * 68];   // per-thread 68-float strip (64 + pad)
    __shared__ float hbuf[32 * 20];
    __shared__ float gacc[32];
    __shared__ float cbuf[8];

    const int tid = threadIdx.x;
    const int b = blockIdx.x;
    const int cg = tid & 31;   // column group: 16 cols each
    const int rg = tid >> 5;   // row group: 4 rows each, 8 groups = 32 rows

    // Global gate-row indices for this thread's 4 rows.
    int grow[4];
    #pragma unroll
    for (int r = 0; r < 4; r++) {
        int rl = rg * 4 + r;                    // row_local in [0,32)
        grow[r] = (rl >> 3) * 512 + b * 8 + (rl & 7);
    }

    // Stage this thread's weight slice into its PRIVATE LDS strip (one-time).
    // Reads coalesced across the wave per (r,cq); strip stride 68 words
    // (68%32=4) -> measured 0 bank conflicts with this pattern (round 6).
    {
        float* wp = &wlds[tid * 68];
        #pragma unroll
        for (int r = 0; r < 4; r++)
            #pragma unroll
            for (int cq = 0; cq < 4; cq++) {
                f32x4 v = *(const f32x4*)&W_hh[(size_t)grow[r] * 512 + cg * 16 + cq * 4];
                *(f32x4*)&wp[r * 16 + cq * 4] = v;
            }
    }

    if (tid < 8) cbuf[tid] = c0[63 * 512 + b * 8 + tid];
    __syncthreads();

    const float* wq = &wlds[tid * 68];

    for (int t = 0; t < 512; t++) {
        // Prefetch xg for this step (independent of h -> overlaps the wait).
        float xgp[4];
        if (cg == 0) {
            #pragma unroll
            for (int r = 0; r < 4; r++)
                xgp[r] = xg[(size_t)t * 2048 + grow[r]];
        }

        if (t == 0) {
            hbuf[HIDX(tid)]       = h0[63 * 512 + tid];
            hbuf[HIDX(tid + 256)] = h0[63 * 512 + tid + 256];
        } else {
            // Poll tagged slots of step t-1 (tag == t) in buffer (t-1)&1.
            u64* src = ((t - 1) & 1) ? sB : sA;
            u64* p0 = &src[tid];
            u64* p1 = &src[tid + 256];
            const unsigned int expt = (unsigned int)t;
            u64 v0, v1;
            for (;;) {
                v0 = __hip_atomic_load(p0, __ATOMIC_RELAXED, __HIP_MEMORY_SCOPE_AGENT);
                v1 = __hip_atomic_load(p1, __ATOMIC_RELAXED, __HIP_MEMORY_SCOPE_AGENT);
                if ((unsigned int)(v0 >> 32) == expt &&
                    (unsigned int)(v1 >> 32) == expt) break;
            }
            hbuf[HIDX(tid)]       = __uint_as_float((unsigned int)v0);
            hbuf[HIDX(tid + 256)] = __uint_as_float((unsigned int)v1);
        }
        __syncthreads();

        // h fragment from LDS.
        f32x4 hv[4];
        #pragma unroll
        for (int cq = 0; cq < 4; cq++)
            hv[cq] = *(const f32x4*)&hbuf[cg * 20 + cq * 4];

        // 4 rows x 16 cols of FMA; weights from the private LDS strip
        // (ds_read_b128 x16, conflict-free, overlaps the FMA chain).
        float acc[4];
        #pragma unroll
        for (int r = 0; r < 4; r++) {
            float s = 0.f;
            #pragma unroll
            for (int cq = 0; cq < 4; cq++) {
                f32x4 wv = *(const f32x4*)&wq[r * 16 + cq * 4];
                s += wv.x * hv[cq].x;
                s += wv.y * hv[cq].y;
                s += wv.z * hv[cq].z;
                s += wv.w * hv[cq].w;
            }
            acc[r] = s;
        }

        // Reduce over the 32 column-group lanes (xor masks <=16 stay in half-wave).
        #pragma unroll
        for (int r = 0; r < 4; r++) {
            #pragma unroll
            for (int m = 16; m >= 1; m >>= 1)
                acc[r] += __shfl_xor(acc[r], m, 64);
        }
        if (cg == 0) {
            #pragma unroll
            for (int r = 0; r < 4; r++)
                gacc[rg * 4 + r] = acc[r] + xgp[r];   // gacc index == q*8 + j
        }
        __syncthreads();

        // Gate tail on lanes 0..7 (wave 0). Torch order: i, f, g, o.
        if (tid < 8) {
            float gi = gacc[tid];
            float gf = gacc[8 + tid];
            float gc = gacc[16 + tid];
            float go = gacc[24 + tid];
            float ii = 1.f / (1.f + __expf(-gi));
            float ff = 1.f / (1.f + __expf(-gf));
            float cc = 1.f - 2.f / (__expf(2.f * gc) + 1.f);   // tanh
            float oo = 1.f / (1.f + __expf(-go));
            float cn = ff * cbuf[tid] + ii * cc;
            cbuf[tid] = cn;
            float th = 1.f - 2.f / (__expf(2.f * cn) + 1.f);   // tanh
            float hval = oo * th;

            // Publish FIRST (critical path), history store after.
            u64* dst = (t & 1) ? sB : sA;
            u64 pv =
                ((u64)(unsigned int)(t + 1) << 32) |
                (u64)__float_as_uint(hval);
            __hip_atomic_store(&dst[b * 8 + tid], pv,
                               __ATOMIC_RELAXED, __HIP_MEMORY_SCOPE_AGENT);

            hs[(size_t)t * 512 + b * 8 + tid] = hval;
        }
        // NO __threadfence, NO flag store.
    }
}

// ---------------------------------------------------------------------------
// Kernel 3: out[s][u] = hs[s] . W_lin[u] + b_lin[u], S=512, T=2. (unchanged)
// ---------------------------------------------------------------------------
__global__ __launch_bounds__(256) void final_linear_k(
    const float* __restrict__ hs, const float* __restrict__ W_lin,
    const float* __restrict__ b_lin, float* __restrict__ out)
{
    const int tid = threadIdx.x;
    const int wave = tid >> 6;
    const int lane = tid & 63;
    const int s = blockIdx.x * 4 + wave;
    const float* h = hs + (size_t)s * 512;
    float a0 = 0.f, a1 = 0.f;
    #pragma unroll
    for (int k0 = 0; k0 < 512; k0 += 64) {
        float hv = h[k0 + lane];
        a0 += hv * W_lin[k0 + lane];
        a1 += hv * W_lin[512 + k0 + lane];
    }
    #pragma unroll
    for (int m = 32; m >= 1; m >>= 1) {
        a0 += __shfl_xor(a0, m, 64);
        a1 += __shfl_xor(a1, m, 64);
    }
    if (lane == 0) {
        out[s * 2]     = a0 + b_lin[0];
        out[s * 2 + 1] = a1 + b_lin[1];
    }
}

// ---------------------------------------------------------------------------
extern "C" void kernel_launch(void* const* d_in, const int* in_sizes, int n_in,
                              void* d_out, int out_size, void* d_ws, size_t ws_size,
                              hipStream_t stream)
{
    const int*   sent  = (const int*)d_in[0];     // [64,512] int32
    const float* h0    = (const float*)d_in[1];   // [1,64,512]
    const float* c0    = (const float*)d_in[2];   // [1,64,512]
    const float* emb   = (const float*)d_in[3];   // [32000,512]
    const float* W_ih  = (const float*)d_in[4];   // [2048,512]
    const float* W_hh  = (const float*)d_in[5];   // [2048,512]
    const float* b_ih  = (const float*)d_in[6];   // [2048]
    const float* b_hh  = (const float*)d_in[7];   // [2048]
    const float* W_lin = (const float*)d_in[8];   // [2,512]
    const float* b_lin = (const float*)d_in[9];   // [2]
    float* out = (float*)d_out;                   // [512,2]

    char* ws = (char*)d_ws;
    float* xg = (float*)ws;                                   // 4 MB: [512,2048]
    float* hs = (float*)(ws + 4 * 1024 * 1024);               // 1 MB: [512,512]
    u64* sA = (u64*)(ws + 5 * 1024 * 1024);                   // 4 KB
    u64* sB = (u64*)(ws + 5 * 1024 * 1024 + 4096);            // 4 KB

    // Clear slot tags (0 != any expected tag 1..512).
    hipMemsetAsync(sA, 0, 2 * 4096, stream);

    dim3 g1(8, 32);
    xg_gemm_k<<<g1, 256, 0, stream>>>(sent, emb, W_ih, b_ih, b_hh, xg);
    lstm_seq_k<<<NB, 256, 0, stream>>>(h0, c0, W_hh, xg, hs, sA, sB);
    final_linear_k<<<128, 256, 0, stream>>>(hs, W_lin, b_lin, out);
}